// Round 1
// baseline (558.438 us; speedup 1.0000x reference)
//
#include <hip/hip_runtime.h>
#include <math.h>

// Problem constants
#define B_ 4
#define HH 64
#define WW 64
#define LL 4096          // H*W
#define DM 96            // d_model
#define DI 192           // d_inner
#define NS 16            // n_state
#define RR 6             // r_rank
#define KK 4             // directions
#define NCH 64           // number of chunks
#define CHL 64           // chunk length (NCH*CHL == LL)

__device__ __forceinline__ int pix_of(int k, int l) {
    // map scan index l (direction k) -> row-major pixel index
    switch (k) {
        case 0: return l;
        case 1: { int w = l >> 6, h = l & 63; return (h << 6) + w; }
        case 2: return (LL - 1) - l;
        default: { int ll = (LL - 1) - l; int w = ll >> 6, h = ll & 63; return (h << 6) + w; }
    }
}

__device__ __forceinline__ float silu_f(float v) {
    return v / (1.f + expf(-v));
}

// ---------------- GEMM: C[M,N] = A[M,K] * Bw[N,K]^T ----------------
// MODE 0: in_proj epilogue (split cols: <192 -> C0 raw, >=192 -> C1 silu)
// MODE 1: plain store to C0 (M,N)
template<int MODE>
__global__ __launch_bounds__(256)
void gemm_kernel(const float* __restrict__ A, const float* __restrict__ Bw,
                 float* __restrict__ C0, float* __restrict__ C1,
                 int M, int N, int Kd) {
    __shared__ float As[64][33];
    __shared__ float Bs[64][33];
    int tid = threadIdx.x;
    int tx = tid & 15, ty = tid >> 4;
    int m0 = blockIdx.y * 64, n0 = blockIdx.x * 64;
    float acc[4][4] = {};
    for (int k0 = 0; k0 < Kd; k0 += 32) {
        #pragma unroll
        for (int i = 0; i < 8; ++i) {
            int idx = tid + i * 256;
            int r = idx >> 5, c = idx & 31;
            As[r][c] = A[(size_t)(m0 + r) * Kd + k0 + c];
            int rn = n0 + r;
            Bs[r][c] = (rn < N) ? Bw[(size_t)rn * Kd + k0 + c] : 0.f;
        }
        __syncthreads();
        #pragma unroll
        for (int kk = 0; kk < 32; ++kk) {
            float av[4], bv[4];
            #pragma unroll
            for (int i = 0; i < 4; ++i) av[i] = As[ty * 4 + i][kk];
            #pragma unroll
            for (int j = 0; j < 4; ++j) bv[j] = Bs[tx * 4 + j][kk];
            #pragma unroll
            for (int i = 0; i < 4; ++i)
                #pragma unroll
                for (int j = 0; j < 4; ++j)
                    acc[i][j] += av[i] * bv[j];
        }
        __syncthreads();
    }
    #pragma unroll
    for (int i = 0; i < 4; ++i) {
        int m = m0 + ty * 4 + i;
        #pragma unroll
        for (int j = 0; j < 4; ++j) {
            int n = n0 + tx * 4 + j;
            if (n >= N) continue;
            float v = acc[i][j];
            if (MODE == 0) {
                if (n < DI) C0[(size_t)m * DI + n] = v;
                else        C1[(size_t)m * DI + (n - DI)] = silu_f(v);
            } else {
                C0[(size_t)m * N + n] = v;
            }
        }
    }
}

// ---------------- Depthwise 3x3 conv + bias + SiLU (channel-last) ----------------
__global__ __launch_bounds__(192)
void conv_kernel(const float* __restrict__ xc, const float* __restrict__ cw,
                 const float* __restrict__ cb, float* __restrict__ out) {
    int p = blockIdx.x;          // pixel
    int b = blockIdx.y;
    int c = threadIdx.x;         // channel
    int h = p >> 6, w = p & 63;
    float acc = cb[c];
    #pragma unroll
    for (int dh = -1; dh <= 1; ++dh) {
        int hh = h + dh;
        if (hh < 0 || hh >= HH) continue;
        #pragma unroll
        for (int dw = -1; dw <= 1; ++dw) {
            int ww = w + dw;
            if (ww < 0 || ww >= WW) continue;
            acc += xc[((size_t)(b << 12) + (hh << 6) + ww) * DI + c] *
                   cw[c * 9 + (dh + 1) * 3 + (dw + 1)];
        }
    }
    out[((size_t)(b << 12) + p) * DI + c] = silu_f(acc);
}

// ---------------- x_dbl projection: per (b,k,l): 192 -> 38 ----------------
// xdbl layout: (b,k,l,38)
__global__ __launch_bounds__(256)
void xdbl_kernel(const float* __restrict__ xconv, const float* __restrict__ xpw,
                 float* __restrict__ xdbl) {
    int lt = blockIdx.x;   // tile of 16 l's
    int k = blockIdx.y;
    int b = blockIdx.z;
    int l0 = lt * 16;
    __shared__ float s_w[38 * 193];
    __shared__ float s_x[16][192];
    int tid = threadIdx.x;
    for (int idx = tid; idx < 38 * 192; idx += 256) {
        int c = idx / 192, dd = idx - c * 192;
        s_w[c * 193 + dd] = xpw[k * 38 * 192 + idx];
    }
    for (int idx = tid; idx < 16 * 192; idx += 256) {
        int i = idx / 192, c = idx - i * 192;
        int p = pix_of(k, l0 + i);
        s_x[i][c] = xconv[((size_t)(b << 12) + p) * DI + c];
    }
    __syncthreads();
    for (int o = tid; o < 16 * 38; o += 256) {
        int i = o / 38, c = o - i * 38;
        float acc = 0.f;
        #pragma unroll 8
        for (int dd = 0; dd < 192; ++dd) acc += s_x[i][dd] * s_w[c * 193 + dd];
        xdbl[((size_t)((b * KK + k) << 12) + l0 + i) * 38 + c] = acc;
    }
}

// ---------------- Scan phases ----------------
// carry layout: [row (b*K+k)*192+d][chunk][n]
template<int PHASE>
__global__ __launch_bounds__(192)
void scan_phase(const float* __restrict__ xconv, const float* __restrict__ xdbl,
                const float* __restrict__ dtw, const float* __restrict__ dtb,
                const float* __restrict__ A_logs, const float* __restrict__ Ds,
                float* __restrict__ carryA, float* __restrict__ carryB,
                float* __restrict__ y_acc) {
    int chunk = blockIdx.x;
    int k = blockIdx.y;
    int b = blockIdx.z;
    int d = threadIdx.x;
    int l0 = chunk * CHL;
    __shared__ float sx[CHL * 38];
    const float* gx = xdbl + ((size_t)((b * KK + k) << 12) + l0) * 38;
    for (int idx = d; idx < CHL * 38; idx += 192) sx[idx] = gx[idx];

    float wr[RR];
    #pragma unroll
    for (int r = 0; r < RR; ++r) wr[r] = dtw[(k * DI + d) * RR + r];
    float bias = dtb[k * DI + d];
    float An[NS], h[NS], ap[NS];
    #pragma unroll
    for (int n = 0; n < NS; ++n) An[n] = -expf(A_logs[(k * DI + d) * NS + n]);
    int row = (b * KK + k) * DI + d;
    if (PHASE == 1) {
        #pragma unroll
        for (int n = 0; n < NS; ++n) { h[n] = 0.f; ap[n] = 1.f; }
    } else {
        #pragma unroll
        for (int n = 0; n < NS; ++n) h[n] = carryB[((size_t)row * NCH + chunk) * NS + n];
        #pragma unroll
        for (int n = 0; n < NS; ++n) ap[n] = 0.f;  // unused
    }
    float Dk = (PHASE == 3) ? Ds[k * DI + d] : 0.f;
    __syncthreads();

    for (int i = 0; i < CHL; ++i) {
        int l = l0 + i;
        int p = pix_of(k, l);
        float u = xconv[((size_t)(b << 12) + p) * DI + d];
        const float* xr = &sx[i * 38];
        float dtraw = bias;
        #pragma unroll
        for (int r = 0; r < RR; ++r) dtraw += xr[r] * wr[r];
        float delta = (dtraw > 20.f) ? dtraw : log1pf(expf(dtraw));
        float du = delta * u;
        float y = 0.f;
        #pragma unroll
        for (int n = 0; n < NS; ++n) {
            float a = expf(delta * An[n]);
            if (PHASE == 1) ap[n] *= a;
            h[n] = a * h[n] + du * xr[6 + n];
            if (PHASE == 3) y += h[n] * xr[22 + n];
        }
        if (PHASE == 3) {
            y += u * Dk;
            atomicAdd(&y_acc[((size_t)(b << 12) + p) * DI + d], y);
        }
    }
    if (PHASE == 1) {
        #pragma unroll
        for (int n = 0; n < NS; ++n) {
            carryA[((size_t)row * NCH + chunk) * NS + n] = ap[n];
            carryB[((size_t)row * NCH + chunk) * NS + n] = h[n];
        }
    }
}

// ---------------- Phase 2: sequential scan over chunks ----------------
__global__ __launch_bounds__(256)
void scan_chunks(const float* __restrict__ carryA, float* __restrict__ carryB) {
    int t = blockIdx.x * 256 + threadIdx.x;
    if (t >= B_ * KK * DI * NS) return;
    int row = t >> 4, n = t & 15;
    float h = 0.f;
    for (int c = 0; c < NCH; ++c) {
        size_t idx = ((size_t)row * NCH + c) * NS + n;
        float a = carryA[idx], bb = carryB[idx];
        carryB[idx] = h;       // exclusive prefix = h_in for chunk c
        h = a * h + bb;
    }
}

// ---------------- zero ----------------
__global__ __launch_bounds__(256)
void zero_kernel(float* __restrict__ p, int n) {
    int i = blockIdx.x * 256 + threadIdx.x;
    if (i < n) p[i] = 0.f;
}

// ---------------- LayerNorm * z ----------------
__global__ __launch_bounds__(256)
void ln_kernel(const float* __restrict__ y_acc, const float* __restrict__ z_silu,
               const float* __restrict__ nw, const float* __restrict__ nb,
               float* __restrict__ out) {
    int pg = blockIdx.x * 4 + (threadIdx.x >> 6);   // pixel (global over B*L)
    int lane = threadIdx.x & 63;
    const float* yr = y_acc + (size_t)pg * DI;
    float v0 = yr[lane], v1 = yr[lane + 64], v2 = yr[lane + 128];
    float s = v0 + v1 + v2;
    float sq = v0 * v0 + v1 * v1 + v2 * v2;
    #pragma unroll
    for (int m = 32; m >= 1; m >>= 1) {
        s  += __shfl_xor(s, m, 64);
        sq += __shfl_xor(sq, m, 64);
    }
    float mu = s * (1.f / 192.f);
    float var = sq * (1.f / 192.f) - mu * mu;
    float rs = rsqrtf(var + 1e-5f);
    const float* zr = z_silu + (size_t)pg * DI;
    float* o = out + (size_t)pg * DI;
    float vv[3] = {v0, v1, v2};
    #pragma unroll
    for (int j = 0; j < 3; ++j) {
        int c = lane + j * 64;
        o[c] = (nw[c] * (vv[j] - mu) * rs + nb[c]) * zr[c];
    }
}

extern "C" void kernel_launch(void* const* d_in, const int* in_sizes, int n_in,
                              void* d_out, int out_size, void* d_ws, size_t ws_size,
                              hipStream_t stream) {
    const float* x        = (const float*)d_in[0];
    const float* in_projw = (const float*)d_in[1];
    const float* conv_w   = (const float*)d_in[2];
    const float* conv_b   = (const float*)d_in[3];
    const float* x_projw  = (const float*)d_in[4];
    const float* dt_w     = (const float*)d_in[5];
    const float* dt_b     = (const float*)d_in[6];
    const float* A_logs   = (const float*)d_in[7];
    const float* Ds       = (const float*)d_in[8];
    const float* nw       = (const float*)d_in[9];
    const float* nb       = (const float*)d_in[10];
    const float* opw      = (const float*)d_in[11];
    float* out = (float*)d_out;
    float* ws = (float*)d_ws;

    const size_t SZ = (size_t)B_ * LL * DI;  // 3,145,728 floats
    float* z_silu = ws;
    float* xc_raw = ws + SZ;        // reused as y_acc after conv
    float* xconv  = ws + 2 * SZ;
    float* carryA = ws + 3 * SZ;    // reused as yln after phase2
    float* carryB = ws + 4 * SZ;
    float* xdbl   = ws + 5 * SZ;    // B*K*L*38 = 2,490,368 floats
    float* y_acc  = xc_raw;
    float* yln    = carryA;

    // 1. in_proj GEMM: (16384,96) x (384,96)^T -> split xc_raw / silu(z)
    gemm_kernel<0><<<dim3(6, 256), 256, 0, stream>>>(x, in_projw, xc_raw, z_silu,
                                                     B_ * LL, 2 * DI, DM);
    // 2. depthwise conv + SiLU
    conv_kernel<<<dim3(LL, B_), DI, 0, stream>>>(xc_raw, conv_w, conv_b, xconv);
    // 3. x_dbl projection
    xdbl_kernel<<<dim3(LL / 16, KK, B_), 256, 0, stream>>>(xconv, x_projw, xdbl);
    // 4. scan phase 1 (local chunk scans -> carries)
    scan_phase<1><<<dim3(NCH, KK, B_), DI, 0, stream>>>(xconv, xdbl, dt_w, dt_b,
                                                        A_logs, Ds, carryA, carryB, nullptr);
    // 5. scan phase 2 (scan across chunks; carryB becomes h_in)
    scan_chunks<<<(B_ * KK * DI * NS + 255) / 256, 256, 0, stream>>>(carryA, carryB);
    // 6. zero accumulator
    zero_kernel<<<(int)(SZ / 256), 256, 0, stream>>>(y_acc, (int)SZ);
    // 7. scan phase 3 (replay with carry-in, scatter-add y)
    scan_phase<3><<<dim3(NCH, KK, B_), DI, 0, stream>>>(xconv, xdbl, dt_w, dt_b,
                                                        A_logs, Ds, carryA, carryB, y_acc);
    // 8. LayerNorm * z
    ln_kernel<<<(B_ * LL) / 4, 256, 0, stream>>>(y_acc, z_silu, nw, nb, yln);
    // 9. out_proj GEMM: (16384,192) x (96,192)^T -> out
    gemm_kernel<1><<<dim3(2, 256), 256, 0, stream>>>(yln, opw, out, nullptr,
                                                     B_ * LL, DM, DI);
}

// Round 2
// 323.645 us; speedup vs baseline: 1.7255x; 1.7255x over previous
//
#include <hip/hip_runtime.h>
#include <math.h>

// Problem constants
#define B_ 4
#define HH 64
#define WW 64
#define LL 4096          // H*W
#define DM 96            // d_model
#define DI 192           // d_inner
#define NS 16            // n_state
#define RR 6             // r_rank
#define KK 4             // directions
#define NROW (B_ * KK * DI)   // 3072 scan rows

__device__ __forceinline__ int pix_of(int k, int l) {
    switch (k) {
        case 0: return l;
        case 1: { int w = l >> 6, h = l & 63; return (h << 6) + w; }
        case 2: return (LL - 1) - l;
        default: { int ll = (LL - 1) - l; int w = ll >> 6, h = ll & 63; return (h << 6) + w; }
    }
}

// Fast math (native v_exp_f32 / v_log_f32 / v_rcp_f32)
__device__ __forceinline__ float silu_f(float v) {
    return v * __fdividef(1.f, 1.f + __expf(-v));
}
__device__ __forceinline__ float softplus_f(float x) {
    return (x > 20.f) ? x : __logf(1.f + __expf(x));
}

// ---------------- GEMM: C[M,N] = A[M,K] * Bw[N,K]^T ----------------
template<int MODE>
__global__ __launch_bounds__(256)
void gemm_kernel(const float* __restrict__ A, const float* __restrict__ Bw,
                 float* __restrict__ C0, float* __restrict__ C1,
                 int M, int N, int Kd) {
    __shared__ float As[64][33];
    __shared__ float Bs[64][33];
    int tid = threadIdx.x;
    int tx = tid & 15, ty = tid >> 4;
    int m0 = blockIdx.y * 64, n0 = blockIdx.x * 64;
    float acc[4][4] = {};
    for (int k0 = 0; k0 < Kd; k0 += 32) {
        #pragma unroll
        for (int i = 0; i < 8; ++i) {
            int idx = tid + i * 256;
            int r = idx >> 5, c = idx & 31;
            As[r][c] = A[(size_t)(m0 + r) * Kd + k0 + c];
            int rn = n0 + r;
            Bs[r][c] = (rn < N) ? Bw[(size_t)rn * Kd + k0 + c] : 0.f;
        }
        __syncthreads();
        #pragma unroll
        for (int kk = 0; kk < 32; ++kk) {
            float av[4], bv[4];
            #pragma unroll
            for (int i = 0; i < 4; ++i) av[i] = As[ty * 4 + i][kk];
            #pragma unroll
            for (int j = 0; j < 4; ++j) bv[j] = Bs[tx * 4 + j][kk];
            #pragma unroll
            for (int i = 0; i < 4; ++i)
                #pragma unroll
                for (int j = 0; j < 4; ++j)
                    acc[i][j] += av[i] * bv[j];
        }
        __syncthreads();
    }
    #pragma unroll
    for (int i = 0; i < 4; ++i) {
        int m = m0 + ty * 4 + i;
        #pragma unroll
        for (int j = 0; j < 4; ++j) {
            int n = n0 + tx * 4 + j;
            if (n >= N) continue;
            float v = acc[i][j];
            if (MODE == 0) {
                if (n < DI) C0[(size_t)m * DI + n] = v;
                else        C1[(size_t)m * DI + (n - DI)] = silu_f(v);
            } else {
                C0[(size_t)m * N + n] = v;
            }
        }
    }
}

// ---------------- Depthwise 3x3 conv + bias + SiLU, 8-pixel row tile ----------------
__global__ __launch_bounds__(192)
void conv_kernel(const float* __restrict__ xc, const float* __restrict__ cw,
                 const float* __restrict__ cb, float* __restrict__ out) {
    int p0 = blockIdx.x * 8;     // 8 pixels, same row (8 | 64)
    int b = blockIdx.y;
    int c = threadIdx.x;
    int h = p0 >> 6, w0 = p0 & 63;
    float kw[9];
    #pragma unroll
    for (int j = 0; j < 9; ++j) kw[j] = cw[c * 9 + j];
    float xv[3][10];
    #pragma unroll
    for (int dh = 0; dh < 3; ++dh) {
        int hh = h + dh - 1;
        bool hv = (hh >= 0 && hh < HH);
        #pragma unroll
        for (int j = 0; j < 10; ++j) {
            int ww = w0 + j - 1;
            bool v = hv && (ww >= 0 && ww < WW);
            xv[dh][j] = v ? xc[((size_t)(b << 12) + (hh << 6) + ww) * DI + c] : 0.f;
        }
    }
    float bias = cb[c];
    #pragma unroll
    for (int w = 0; w < 8; ++w) {
        float acc = bias;
        #pragma unroll
        for (int dh = 0; dh < 3; ++dh)
            #pragma unroll
            for (int dc = 0; dc < 3; ++dc)
                acc += xv[dh][w + dc] * kw[dh * 3 + dc];
        out[((size_t)(b << 12) + p0 + w) * DI + c] = silu_f(acc);
    }
}

// ---------------- x_dbl projection: per (b,k,l): 192 -> 38 ----------------
__global__ __launch_bounds__(256)
void xdbl_kernel(const float* __restrict__ xconv, const float* __restrict__ xpw,
                 float* __restrict__ xdbl) {
    int lt = blockIdx.x;
    int k = blockIdx.y;
    int b = blockIdx.z;
    int l0 = lt * 16;
    __shared__ float s_w[38 * 193];
    __shared__ float s_x[16][193];     // pad 193: avoid 7-way bank conflict
    int tid = threadIdx.x;
    for (int idx = tid; idx < 38 * 192; idx += 256) {
        int c = idx / 192, dd = idx - c * 192;
        s_w[c * 193 + dd] = xpw[k * 38 * 192 + idx];
    }
    for (int idx = tid; idx < 16 * 192; idx += 256) {
        int i = idx / 192, c = idx - i * 192;
        int p = pix_of(k, l0 + i);
        s_x[i][c] = xconv[((size_t)(b << 12) + p) * DI + c];
    }
    __syncthreads();
    for (int o = tid; o < 16 * 38; o += 256) {
        int i = o / 38, c = o - i * 38;
        float acc = 0.f;
        #pragma unroll 8
        for (int dd = 0; dd < 192; ++dd) acc += s_x[i][dd] * s_w[c * 193 + dd];
        xdbl[((size_t)((b * KK + k) << 12) + l0 + i) * 38 + c] = acc;
    }
}

// ---------------- Scan phases ----------------
// carry layout: [chunk][row][n], row = (b*K+k)*DI+d  (coalesced everywhere)
template<int PHASE, int NCHT>
__global__ __launch_bounds__(192)
void scan_phase(const float* __restrict__ xconv, const float* __restrict__ xdbl,
                const float* __restrict__ dtw, const float* __restrict__ dtb,
                const float* __restrict__ A_logs, const float* __restrict__ Ds,
                float* __restrict__ carryA, float* __restrict__ carryB,
                float* __restrict__ y_acc) {
    constexpr int CHL = LL / NCHT;
    int chunk = blockIdx.x;
    int k = blockIdx.y;
    int b = blockIdx.z;
    int d = threadIdx.x;
    int l0 = chunk * CHL;
    __shared__ float sx[CHL * 38];
    const float* gx = xdbl + ((size_t)((b * KK + k) << 12) + l0) * 38;
    for (int idx = d; idx < CHL * 38; idx += DI) sx[idx] = gx[idx];

    float wr[RR];
    #pragma unroll
    for (int r = 0; r < RR; ++r) wr[r] = dtw[(k * DI + d) * RR + r];
    float bias = dtb[k * DI + d];
    float An[NS], h[NS], ap[NS];
    #pragma unroll
    for (int n = 0; n < NS; ++n) An[n] = -__expf(A_logs[(k * DI + d) * NS + n]);
    int row = (b * KK + k) * DI + d;
    if (PHASE == 1) {
        #pragma unroll
        for (int n = 0; n < NS; ++n) { h[n] = 0.f; ap[n] = 1.f; }
    } else {
        #pragma unroll
        for (int n = 0; n < NS; ++n) h[n] = carryB[((size_t)chunk * NROW + row) * NS + n];
    }
    float Dk = (PHASE == 3) ? Ds[k * DI + d] : 0.f;
    __syncthreads();

    for (int i = 0; i < CHL; ++i) {
        int l = l0 + i;
        int p = pix_of(k, l);
        float u = xconv[((size_t)(b << 12) + p) * DI + d];
        const float* xr = &sx[i * 38];
        float dtraw = bias;
        #pragma unroll
        for (int r = 0; r < RR; ++r) dtraw += xr[r] * wr[r];
        float delta = softplus_f(dtraw);
        float du = delta * u;
        float y = 0.f;
        #pragma unroll
        for (int n = 0; n < NS; ++n) {
            float a = __expf(delta * An[n]);
            if (PHASE == 1) ap[n] *= a;
            h[n] = a * h[n] + du * xr[6 + n];
            if (PHASE == 3) y += h[n] * xr[22 + n];
        }
        if (PHASE == 3) {
            y += u * Dk;
            atomicAdd(&y_acc[((size_t)(b << 12) + p) * DI + d], y);
        }
    }
    if (PHASE == 1) {
        #pragma unroll
        for (int n = 0; n < NS; ++n) {
            carryA[((size_t)chunk * NROW + row) * NS + n] = ap[n];
            carryB[((size_t)chunk * NROW + row) * NS + n] = h[n];
        }
    }
}

// ---------------- Phase 2: sequential scan over chunk carries ----------------
template<int NCHT>
__global__ __launch_bounds__(256)
void scan_chunks(const float* __restrict__ carryA, float* __restrict__ carryB) {
    int t = blockIdx.x * 256 + threadIdx.x;
    if (t >= NROW * NS) return;
    float h = 0.f;
    for (int c = 0; c < NCHT; ++c) {
        size_t idx = (size_t)c * (NROW * NS) + t;
        float a = carryA[idx], bb = carryB[idx];
        carryB[idx] = h;       // exclusive prefix = h_in for chunk c
        h = a * h + bb;
    }
}

__global__ __launch_bounds__(256)
void zero_kernel(float* __restrict__ p, int n) {
    int i = blockIdx.x * 256 + threadIdx.x;
    if (i < n) p[i] = 0.f;
}

// ---------------- LayerNorm * z ----------------
__global__ __launch_bounds__(256)
void ln_kernel(const float* __restrict__ y_acc, const float* __restrict__ z_silu,
               const float* __restrict__ nw, const float* __restrict__ nb,
               float* __restrict__ out) {
    int pg = blockIdx.x * 4 + (threadIdx.x >> 6);
    int lane = threadIdx.x & 63;
    const float* yr = y_acc + (size_t)pg * DI;
    float v0 = yr[lane], v1 = yr[lane + 64], v2 = yr[lane + 128];
    float s = v0 + v1 + v2;
    float sq = v0 * v0 + v1 * v1 + v2 * v2;
    #pragma unroll
    for (int m = 32; m >= 1; m >>= 1) {
        s  += __shfl_xor(s, m, 64);
        sq += __shfl_xor(sq, m, 64);
    }
    float mu = s * (1.f / 192.f);
    float var = sq * (1.f / 192.f) - mu * mu;
    float rs = rsqrtf(var + 1e-5f);
    const float* zr = z_silu + (size_t)pg * DI;
    float* o = out + (size_t)pg * DI;
    float vv[3] = {v0, v1, v2};
    #pragma unroll
    for (int j = 0; j < 3; ++j) {
        int c = lane + j * 64;
        o[c] = (nw[c] * (vv[j] - mu) * rs + nb[c]) * zr[c];
    }
}

extern "C" void kernel_launch(void* const* d_in, const int* in_sizes, int n_in,
                              void* d_out, int out_size, void* d_ws, size_t ws_size,
                              hipStream_t stream) {
    const float* x        = (const float*)d_in[0];
    const float* in_projw = (const float*)d_in[1];
    const float* conv_w   = (const float*)d_in[2];
    const float* conv_b   = (const float*)d_in[3];
    const float* x_projw  = (const float*)d_in[4];
    const float* dt_w     = (const float*)d_in[5];
    const float* dt_b     = (const float*)d_in[6];
    const float* A_logs   = (const float*)d_in[7];
    const float* Ds       = (const float*)d_in[8];
    const float* nw       = (const float*)d_in[9];
    const float* nb       = (const float*)d_in[10];
    const float* opw      = (const float*)d_in[11];
    float* out = (float*)d_out;
    float* ws = (float*)d_ws;

    const size_t SZ = (size_t)B_ * LL * DI;          // 3,145,728
    const size_t XD = (size_t)B_ * KK * LL * 38;     // 2,490,368

    // choose chunk count by available workspace
    const size_t car128 = (size_t)NROW * 128 * NS;   // 6,291,456 floats
    const size_t need128 = (3 * SZ + XD + 2 * car128) * sizeof(float);
    bool big = (ws_size >= need128);

    float* z_silu = ws;
    float* xc_raw = ws + SZ;            // reused as y_acc
    float* xconv  = ws + 2 * SZ;        // reused as yln after phase 3
    float* xdbl   = ws + 3 * SZ;
    float* carryA = ws + 3 * SZ + XD;
    float* carryB = carryA + (big ? car128 : (size_t)NROW * 64 * NS);
    float* y_acc  = xc_raw;
    float* yln    = xconv;

    gemm_kernel<0><<<dim3(6, 256), 256, 0, stream>>>(x, in_projw, xc_raw, z_silu,
                                                     B_ * LL, 2 * DI, DM);
    conv_kernel<<<dim3(LL / 8, B_), DI, 0, stream>>>(xc_raw, conv_w, conv_b, xconv);
    xdbl_kernel<<<dim3(LL / 16, KK, B_), 256, 0, stream>>>(xconv, x_projw, xdbl);

    if (big) {
        scan_phase<1, 128><<<dim3(128, KK, B_), DI, 0, stream>>>(xconv, xdbl, dt_w, dt_b,
                                                                 A_logs, Ds, carryA, carryB, nullptr);
        scan_chunks<128><<<(NROW * NS + 255) / 256, 256, 0, stream>>>(carryA, carryB);
        zero_kernel<<<(int)(SZ / 256), 256, 0, stream>>>(y_acc, (int)SZ);
        scan_phase<3, 128><<<dim3(128, KK, B_), DI, 0, stream>>>(xconv, xdbl, dt_w, dt_b,
                                                                 A_logs, Ds, carryA, carryB, y_acc);
    } else {
        scan_phase<1, 64><<<dim3(64, KK, B_), DI, 0, stream>>>(xconv, xdbl, dt_w, dt_b,
                                                               A_logs, Ds, carryA, carryB, nullptr);
        scan_chunks<64><<<(NROW * NS + 255) / 256, 256, 0, stream>>>(carryA, carryB);
        zero_kernel<<<(int)(SZ / 256), 256, 0, stream>>>(y_acc, (int)SZ);
        scan_phase<3, 64><<<dim3(64, KK, B_), DI, 0, stream>>>(xconv, xdbl, dt_w, dt_b,
                                                               A_logs, Ds, carryA, carryB, y_acc);
    }
    ln_kernel<<<(B_ * LL) / 4, 256, 0, stream>>>(y_acc, z_silu, nw, nb, yln);
    gemm_kernel<1><<<dim3(2, 256), 256, 0, stream>>>(yln, opw, out, nullptr,
                                                     B_ * LL, DM, DI);
}

// Round 3
// 288.570 us; speedup vs baseline: 1.9352x; 1.1215x over previous
//
#include <hip/hip_runtime.h>
#include <math.h>

// Problem constants
#define B_ 4
#define HH 64
#define WW 64
#define LL 4096          // H*W
#define DM 96            // d_model
#define DI 192           // d_inner
#define NS 16            // n_state
#define RR 6             // r_rank
#define KK 4             // directions
#define NROW (B_ * KK * DI)   // 3072 scan rows

__device__ __forceinline__ int pix_of(int k, int l) {
    switch (k) {
        case 0: return l;
        case 1: { int w = l >> 6, h = l & 63; return (h << 6) + w; }
        case 2: return (LL - 1) - l;
        default: { int ll = (LL - 1) - l; int w = ll >> 6, h = ll & 63; return (h << 6) + w; }
    }
}

// Fast math (native v_exp_f32 / v_log_f32 / v_rcp_f32)
__device__ __forceinline__ float silu_f(float v) {
    return v * __fdividef(1.f, 1.f + __expf(-v));
}
__device__ __forceinline__ float softplus_f(float x) {
    return (x > 20.f) ? x : __logf(1.f + __expf(x));
}

// ---------------- GEMM: C[M,N] = A[M,K] * Bw[N,K]^T ----------------
template<int MODE>
__global__ __launch_bounds__(256)
void gemm_kernel(const float* __restrict__ A, const float* __restrict__ Bw,
                 float* __restrict__ C0, float* __restrict__ C1,
                 int M, int N, int Kd) {
    __shared__ float As[64][33];
    __shared__ float Bs[64][33];
    int tid = threadIdx.x;
    int tx = tid & 15, ty = tid >> 4;
    int m0 = blockIdx.y * 64, n0 = blockIdx.x * 64;
    float acc[4][4] = {};
    for (int k0 = 0; k0 < Kd; k0 += 32) {
        #pragma unroll
        for (int i = 0; i < 8; ++i) {
            int idx = tid + i * 256;
            int r = idx >> 5, c = idx & 31;
            As[r][c] = A[(size_t)(m0 + r) * Kd + k0 + c];
            int rn = n0 + r;
            Bs[r][c] = (rn < N) ? Bw[(size_t)rn * Kd + k0 + c] : 0.f;
        }
        __syncthreads();
        #pragma unroll
        for (int kk = 0; kk < 32; ++kk) {
            float av[4], bv[4];
            #pragma unroll
            for (int i = 0; i < 4; ++i) av[i] = As[ty * 4 + i][kk];
            #pragma unroll
            for (int j = 0; j < 4; ++j) bv[j] = Bs[tx * 4 + j][kk];
            #pragma unroll
            for (int i = 0; i < 4; ++i)
                #pragma unroll
                for (int j = 0; j < 4; ++j)
                    acc[i][j] += av[i] * bv[j];
        }
        __syncthreads();
    }
    #pragma unroll
    for (int i = 0; i < 4; ++i) {
        int m = m0 + ty * 4 + i;
        #pragma unroll
        for (int j = 0; j < 4; ++j) {
            int n = n0 + tx * 4 + j;
            if (n >= N) continue;
            float v = acc[i][j];
            if (MODE == 0) {
                if (n < DI) C0[(size_t)m * DI + n] = v;
                else        C1[(size_t)m * DI + (n - DI)] = silu_f(v);
            } else {
                C0[(size_t)m * N + n] = v;
            }
        }
    }
}

// ---------------- Depthwise 3x3 conv + bias + SiLU, 8-pixel row tile ----------------
__global__ __launch_bounds__(192)
void conv_kernel(const float* __restrict__ xc, const float* __restrict__ cw,
                 const float* __restrict__ cb, float* __restrict__ out) {
    int p0 = blockIdx.x * 8;     // 8 pixels, same row (8 | 64)
    int b = blockIdx.y;
    int c = threadIdx.x;
    int h = p0 >> 6, w0 = p0 & 63;
    float kw[9];
    #pragma unroll
    for (int j = 0; j < 9; ++j) kw[j] = cw[c * 9 + j];
    float xv[3][10];
    #pragma unroll
    for (int dh = 0; dh < 3; ++dh) {
        int hh = h + dh - 1;
        bool hv = (hh >= 0 && hh < HH);
        #pragma unroll
        for (int j = 0; j < 10; ++j) {
            int ww = w0 + j - 1;
            bool v = hv && (ww >= 0 && ww < WW);
            xv[dh][j] = v ? xc[((size_t)(b << 12) + (hh << 6) + ww) * DI + c] : 0.f;
        }
    }
    float bias = cb[c];
    #pragma unroll
    for (int w = 0; w < 8; ++w) {
        float acc = bias;
        #pragma unroll
        for (int dh = 0; dh < 3; ++dh)
            #pragma unroll
            for (int dc = 0; dc < 3; ++dc)
                acc += xv[dh][w + dc] * kw[dh * 3 + dc];
        out[((size_t)(b << 12) + p0 + w) * DI + c] = silu_f(acc);
    }
}

// ---------------- x_dbl projection as register-tiled GEMM ----------------
// Per block: one k, 128 l's, 40 outputs (38 real). 256 thr, thread tile 4x5.
__global__ __launch_bounds__(256)
void xdbl_kernel(const float* __restrict__ xconv, const float* __restrict__ xpw,
                 float* __restrict__ xdbl) {
    __shared__ float s_x[128][33];
    __shared__ float s_w[40][33];
    int k = blockIdx.y;
    int b = blockIdx.z;
    int l0 = blockIdx.x * 128;
    int tid = threadIdx.x;
    int tx = tid & 7, ty = tid >> 3;       // tx: 8 n-groups, ty: 32 l-groups
    float acc[4][5] = {};
    const float* wk = xpw + k * 38 * 192;
    for (int k0 = 0; k0 < 192; k0 += 32) {
        // stage x tile: 128 rows x 32 cols
        #pragma unroll
        for (int it = 0; it < 16; ++it) {
            int idx = tid + it * 256;
            int r = idx >> 5, c = idx & 31;
            int p = pix_of(k, l0 + r);
            s_x[r][c] = xconv[((size_t)(b << 12) + p) * DI + k0 + c];
        }
        // stage w tile: 40 rows x 32 cols
        #pragma unroll
        for (int it = 0; it < 5; ++it) {
            int idx = tid + it * 256;
            int r = idx >> 5, c = idx & 31;
            s_w[r][c] = (r < 38) ? wk[r * 192 + k0 + c] : 0.f;
        }
        __syncthreads();
        #pragma unroll
        for (int kk = 0; kk < 32; ++kk) {
            float av[4], bv[5];
            #pragma unroll
            for (int i = 0; i < 4; ++i) av[i] = s_x[ty * 4 + i][kk];
            #pragma unroll
            for (int j = 0; j < 5; ++j) bv[j] = s_w[tx * 5 + j][kk];
            #pragma unroll
            for (int i = 0; i < 4; ++i)
                #pragma unroll
                for (int j = 0; j < 5; ++j)
                    acc[i][j] += av[i] * bv[j];
        }
        __syncthreads();
    }
    size_t base = (size_t)((b * KK + k) << 12);
    #pragma unroll
    for (int i = 0; i < 4; ++i) {
        int l = l0 + ty * 4 + i;
        #pragma unroll
        for (int j = 0; j < 5; ++j) {
            int c = tx * 5 + j;
            if (c < 38) xdbl[(base + l) * 38 + c] = acc[i][j];
        }
    }
}

// ---------------- Scan phases ----------------
// carry layout: [chunk][row][n], row = (b*K+k)*DI+d  (coalesced everywhere)
template<int PHASE, int NCHT>
__global__ __launch_bounds__(192)
void scan_phase(const float* __restrict__ xconv, const float* __restrict__ xdbl,
                const float* __restrict__ dtw, const float* __restrict__ dtb,
                const float* __restrict__ A_logs, const float* __restrict__ Ds,
                float* __restrict__ carryA, float* __restrict__ carryB,
                float* __restrict__ y_acc) {
    constexpr int CHL = LL / NCHT;
    int chunk = blockIdx.x;
    int k = blockIdx.y;
    int b = blockIdx.z;
    int d = threadIdx.x;
    int l0 = chunk * CHL;
    __shared__ float sx[CHL * 38];
    const float* gx = xdbl + ((size_t)((b * KK + k) << 12) + l0) * 38;
    for (int idx = d; idx < CHL * 38; idx += DI) sx[idx] = gx[idx];

    float wr[RR];
    #pragma unroll
    for (int r = 0; r < RR; ++r) wr[r] = dtw[(k * DI + d) * RR + r];
    float bias = dtb[k * DI + d];
    float An[NS], h[NS], ap[NS];
    #pragma unroll
    for (int n = 0; n < NS; ++n) An[n] = -__expf(A_logs[(k * DI + d) * NS + n]);
    int row = (b * KK + k) * DI + d;
    if (PHASE == 1) {
        #pragma unroll
        for (int n = 0; n < NS; ++n) { h[n] = 0.f; ap[n] = 1.f; }
    } else {
        #pragma unroll
        for (int n = 0; n < NS; ++n) h[n] = carryB[((size_t)chunk * NROW + row) * NS + n];
    }
    float Dk = (PHASE == 3) ? Ds[k * DI + d] : 0.f;
    __syncthreads();

    for (int i = 0; i < CHL; ++i) {
        int l = l0 + i;
        int p = pix_of(k, l);
        float u = xconv[((size_t)(b << 12) + p) * DI + d];
        const float* xr = &sx[i * 38];
        float dtraw = bias;
        #pragma unroll
        for (int r = 0; r < RR; ++r) dtraw += xr[r] * wr[r];
        float delta = softplus_f(dtraw);
        float du = delta * u;
        float y = 0.f;
        #pragma unroll
        for (int n = 0; n < NS; ++n) {
            float a = __expf(delta * An[n]);
            if (PHASE == 1) ap[n] *= a;
            h[n] = a * h[n] + du * xr[6 + n];
            if (PHASE == 3) y += h[n] * xr[22 + n];
        }
        if (PHASE == 3) {
            y += u * Dk;
            atomicAdd(&y_acc[((size_t)(b << 12) + p) * DI + d], y);
        }
    }
    if (PHASE == 1) {
        #pragma unroll
        for (int n = 0; n < NS; ++n) {
            carryA[((size_t)chunk * NROW + row) * NS + n] = ap[n];
            carryB[((size_t)chunk * NROW + row) * NS + n] = h[n];
        }
    }
}

// ---------------- Phase 2: sequential scan over chunk carries ----------------
template<int NCHT>
__global__ __launch_bounds__(256)
void scan_chunks(const float* __restrict__ carryA, float* __restrict__ carryB) {
    int t = blockIdx.x * 256 + threadIdx.x;
    if (t >= NROW * NS) return;
    float h = 0.f;
    for (int c = 0; c < NCHT; ++c) {
        size_t idx = (size_t)c * (NROW * NS) + t;
        float a = carryA[idx], bb = carryB[idx];
        carryB[idx] = h;       // exclusive prefix = h_in for chunk c
        h = a * h + bb;
    }
}

__global__ __launch_bounds__(256)
void zero_kernel(float* __restrict__ p, int n) {
    int i = blockIdx.x * 256 + threadIdx.x;
    if (i < n) p[i] = 0.f;
}

// ---------------- LayerNorm * z ----------------
__global__ __launch_bounds__(256)
void ln_kernel(const float* __restrict__ y_acc, const float* __restrict__ z_silu,
               const float* __restrict__ nw, const float* __restrict__ nb,
               float* __restrict__ out) {
    int pg = blockIdx.x * 4 + (threadIdx.x >> 6);
    int lane = threadIdx.x & 63;
    const float* yr = y_acc + (size_t)pg * DI;
    float v0 = yr[lane], v1 = yr[lane + 64], v2 = yr[lane + 128];
    float s = v0 + v1 + v2;
    float sq = v0 * v0 + v1 * v1 + v2 * v2;
    #pragma unroll
    for (int m = 32; m >= 1; m >>= 1) {
        s  += __shfl_xor(s, m, 64);
        sq += __shfl_xor(sq, m, 64);
    }
    float mu = s * (1.f / 192.f);
    float var = sq * (1.f / 192.f) - mu * mu;
    float rs = rsqrtf(var + 1e-5f);
    const float* zr = z_silu + (size_t)pg * DI;
    float* o = out + (size_t)pg * DI;
    float vv[3] = {v0, v1, v2};
    #pragma unroll
    for (int j = 0; j < 3; ++j) {
        int c = lane + j * 64;
        o[c] = (nw[c] * (vv[j] - mu) * rs + nb[c]) * zr[c];
    }
}

extern "C" void kernel_launch(void* const* d_in, const int* in_sizes, int n_in,
                              void* d_out, int out_size, void* d_ws, size_t ws_size,
                              hipStream_t stream) {
    const float* x        = (const float*)d_in[0];
    const float* in_projw = (const float*)d_in[1];
    const float* conv_w   = (const float*)d_in[2];
    const float* conv_b   = (const float*)d_in[3];
    const float* x_projw  = (const float*)d_in[4];
    const float* dt_w     = (const float*)d_in[5];
    const float* dt_b     = (const float*)d_in[6];
    const float* A_logs   = (const float*)d_in[7];
    const float* Ds       = (const float*)d_in[8];
    const float* nw       = (const float*)d_in[9];
    const float* nb       = (const float*)d_in[10];
    const float* opw      = (const float*)d_in[11];
    float* out = (float*)d_out;
    float* ws = (float*)d_ws;

    const size_t SZ = (size_t)B_ * LL * DI;          // 3,145,728
    const size_t XD = (size_t)B_ * KK * LL * 38;     // 2,490,368

    // choose chunk count by available workspace
    const size_t car128 = (size_t)NROW * 128 * NS;   // 6,291,456 floats
    const size_t need128 = (3 * SZ + XD + 2 * car128) * sizeof(float);
    bool big = (ws_size >= need128);

    float* z_silu = ws;
    float* xc_raw = ws + SZ;            // reused as y_acc
    float* xconv  = ws + 2 * SZ;        // reused as yln after phase 3
    float* xdbl   = ws + 3 * SZ;
    float* carryA = ws + 3 * SZ + XD;
    float* carryB = carryA + (big ? car128 : (size_t)NROW * 64 * NS);
    float* y_acc  = xc_raw;
    float* yln    = xconv;

    gemm_kernel<0><<<dim3(6, 256), 256, 0, stream>>>(x, in_projw, xc_raw, z_silu,
                                                     B_ * LL, 2 * DI, DM);
    conv_kernel<<<dim3(LL / 8, B_), DI, 0, stream>>>(xc_raw, conv_w, conv_b, xconv);
    xdbl_kernel<<<dim3(LL / 128, KK, B_), 256, 0, stream>>>(xconv, x_projw, xdbl);

    if (big) {
        scan_phase<1, 128><<<dim3(128, KK, B_), DI, 0, stream>>>(xconv, xdbl, dt_w, dt_b,
                                                                 A_logs, Ds, carryA, carryB, nullptr);
        scan_chunks<128><<<(NROW * NS + 255) / 256, 256, 0, stream>>>(carryA, carryB);
        zero_kernel<<<(int)(SZ / 256), 256, 0, stream>>>(y_acc, (int)SZ);
        scan_phase<3, 128><<<dim3(128, KK, B_), DI, 0, stream>>>(xconv, xdbl, dt_w, dt_b,
                                                                 A_logs, Ds, carryA, carryB, y_acc);
    } else {
        scan_phase<1, 64><<<dim3(64, KK, B_), DI, 0, stream>>>(xconv, xdbl, dt_w, dt_b,
                                                               A_logs, Ds, carryA, carryB, nullptr);
        scan_chunks<64><<<(NROW * NS + 255) / 256, 256, 0, stream>>>(carryA, carryB);
        zero_kernel<<<(int)(SZ / 256), 256, 0, stream>>>(y_acc, (int)SZ);
        scan_phase<3, 64><<<dim3(64, KK, B_), DI, 0, stream>>>(xconv, xdbl, dt_w, dt_b,
                                                               A_logs, Ds, carryA, carryB, y_acc);
    }
    ln_kernel<<<(B_ * LL) / 4, 256, 0, stream>>>(y_acc, z_silu, nw, nb, yln);
    gemm_kernel<1><<<dim3(2, 256), 256, 0, stream>>>(yln, opw, out, nullptr,
                                                     B_ * LL, DM, DI);
}

// Round 4
// 253.669 us; speedup vs baseline: 2.2014x; 1.1376x over previous
//
#include <hip/hip_runtime.h>
#include <math.h>

// Problem constants
#define B_ 4
#define HH 64
#define WW 64
#define LL 4096          // H*W
#define DM 96            // d_model
#define DI 192           // d_inner
#define NS 16            // n_state
#define RR 6             // r_rank
#define KK 4             // directions
#define NROW (B_ * KK * DI)   // 3072 scan rows
#define XSTR 40          // padded x_dbl row stride (38 real)

__device__ __forceinline__ int pix_of(int k, int l) {
    switch (k) {
        case 0: return l;
        case 1: { int w = l >> 6, h = l & 63; return (h << 6) + w; }
        case 2: return (LL - 1) - l;
        default: { int ll = (LL - 1) - l; int w = ll >> 6, h = ll & 63; return (h << 6) + w; }
    }
}

// Fast math (native v_exp_f32 / v_log_f32 / v_rcp_f32)
__device__ __forceinline__ float silu_f(float v) {
    return v * __fdividef(1.f, 1.f + __expf(-v));
}
__device__ __forceinline__ float softplus_f(float x) {
    return (x > 20.f) ? x : __logf(1.f + __expf(x));
}

// ---------------- GEMM: C[M,N] = A[M,K] * Bw[N,K]^T ----------------
template<int MODE>
__global__ __launch_bounds__(256)
void gemm_kernel(const float* __restrict__ A, const float* __restrict__ Bw,
                 float* __restrict__ C0, float* __restrict__ C1,
                 int M, int N, int Kd) {
    __shared__ float As[64][33];
    __shared__ float Bs[64][33];
    int tid = threadIdx.x;
    int tx = tid & 15, ty = tid >> 4;
    int m0 = blockIdx.y * 64, n0 = blockIdx.x * 64;
    float acc[4][4] = {};
    for (int k0 = 0; k0 < Kd; k0 += 32) {
        #pragma unroll
        for (int i = 0; i < 8; ++i) {
            int idx = tid + i * 256;
            int r = idx >> 5, c = idx & 31;
            As[r][c] = A[(size_t)(m0 + r) * Kd + k0 + c];
            int rn = n0 + r;
            Bs[r][c] = (rn < N) ? Bw[(size_t)rn * Kd + k0 + c] : 0.f;
        }
        __syncthreads();
        #pragma unroll
        for (int kk = 0; kk < 32; ++kk) {
            float av[4], bv[4];
            #pragma unroll
            for (int i = 0; i < 4; ++i) av[i] = As[ty * 4 + i][kk];
            #pragma unroll
            for (int j = 0; j < 4; ++j) bv[j] = Bs[tx * 4 + j][kk];
            #pragma unroll
            for (int i = 0; i < 4; ++i)
                #pragma unroll
                for (int j = 0; j < 4; ++j)
                    acc[i][j] += av[i] * bv[j];
        }
        __syncthreads();
    }
    #pragma unroll
    for (int i = 0; i < 4; ++i) {
        int m = m0 + ty * 4 + i;
        #pragma unroll
        for (int j = 0; j < 4; ++j) {
            int n = n0 + tx * 4 + j;
            if (n >= N) continue;
            float v = acc[i][j];
            if (MODE == 0) {
                if (n < DI) C0[(size_t)m * DI + n] = v;
                else        C1[(size_t)m * DI + (n - DI)] = silu_f(v);
            } else {
                C0[(size_t)m * N + n] = v;
            }
        }
    }
}

// ---------------- Depthwise 3x3 conv + bias + SiLU, 8-pixel row tile ----------------
__global__ __launch_bounds__(192)
void conv_kernel(const float* __restrict__ xc, const float* __restrict__ cw,
                 const float* __restrict__ cb, float* __restrict__ out) {
    int p0 = blockIdx.x * 8;     // 8 pixels, same row (8 | 64)
    int b = blockIdx.y;
    int c = threadIdx.x;
    int h = p0 >> 6, w0 = p0 & 63;
    float kw[9];
    #pragma unroll
    for (int j = 0; j < 9; ++j) kw[j] = cw[c * 9 + j];
    float xv[3][10];
    #pragma unroll
    for (int dh = 0; dh < 3; ++dh) {
        int hh = h + dh - 1;
        bool hv = (hh >= 0 && hh < HH);
        #pragma unroll
        for (int j = 0; j < 10; ++j) {
            int ww = w0 + j - 1;
            bool v = hv && (ww >= 0 && ww < WW);
            xv[dh][j] = v ? xc[((size_t)(b << 12) + (hh << 6) + ww) * DI + c] : 0.f;
        }
    }
    float bias = cb[c];
    #pragma unroll
    for (int w = 0; w < 8; ++w) {
        float acc = bias;
        #pragma unroll
        for (int dh = 0; dh < 3; ++dh)
            #pragma unroll
            for (int dc = 0; dc < 3; ++dc)
                acc += xv[dh][w + dc] * kw[dh * 3 + dc];
        out[((size_t)(b << 12) + p0 + w) * DI + c] = silu_f(acc);
    }
}

// ---------------- x_dbl projection as register-tiled GEMM ----------------
// Per block: one k, 128 l's, 40 outputs (38 real). 256 thr, thread tile 4x5.
__global__ __launch_bounds__(256)
void xdbl_kernel(const float* __restrict__ xconv, const float* __restrict__ xpw,
                 float* __restrict__ xdbl) {
    __shared__ float s_x[128][33];
    __shared__ float s_w[40][33];
    int k = blockIdx.y;
    int b = blockIdx.z;
    int l0 = blockIdx.x * 128;
    int tid = threadIdx.x;
    int tx = tid & 7, ty = tid >> 3;       // tx: 8 n-groups, ty: 32 l-groups
    float acc[4][5] = {};
    const float* wk = xpw + k * 38 * 192;
    for (int k0 = 0; k0 < 192; k0 += 32) {
        // stage x tile: 128 rows x 32 cols
        #pragma unroll
        for (int it = 0; it < 16; ++it) {
            int idx = tid + it * 256;
            int r = idx >> 5, c = idx & 31;
            int p = pix_of(k, l0 + r);
            s_x[r][c] = xconv[((size_t)(b << 12) + p) * DI + k0 + c];
        }
        // stage w tile: 40 rows x 32 cols
        #pragma unroll
        for (int it = 0; it < 5; ++it) {
            int idx = tid + it * 256;
            int r = idx >> 5, c = idx & 31;
            s_w[r][c] = (r < 38) ? wk[r * 192 + k0 + c] : 0.f;
        }
        __syncthreads();
        #pragma unroll
        for (int kk = 0; kk < 32; ++kk) {
            float av[4], bv[5];
            #pragma unroll
            for (int i = 0; i < 4; ++i) av[i] = s_x[ty * 4 + i][kk];
            #pragma unroll
            for (int j = 0; j < 5; ++j) bv[j] = s_w[tx * 5 + j][kk];
            #pragma unroll
            for (int i = 0; i < 4; ++i)
                #pragma unroll
                for (int j = 0; j < 5; ++j)
                    acc[i][j] += av[i] * bv[j];
        }
        __syncthreads();
    }
    size_t base = (size_t)((b * KK + k) << 12);
    #pragma unroll
    for (int i = 0; i < 4; ++i) {
        int l = l0 + ty * 4 + i;
        #pragma unroll
        for (int j = 0; j < 5; ++j) {
            int c = tx * 5 + j;
            if (c < 38) xdbl[(base + l) * XSTR + c] = acc[i][j];
        }
    }
}

// ---------------- Scan phases ----------------
// carry layout: [chunk][row][n], row = (b*K+k)*DI+d  (coalesced everywhere)
template<int PHASE, int NCHT>
__global__ __launch_bounds__(192)
void scan_phase(const float* __restrict__ xconv, const float* __restrict__ xdbl,
                const float* __restrict__ dtw, const float* __restrict__ dtb,
                const float* __restrict__ A_logs, const float* __restrict__ Ds,
                float* __restrict__ carryA, float* __restrict__ carryB,
                float* __restrict__ y_acc) {
    constexpr int CHL = LL / NCHT;
    int chunk = blockIdx.x;
    int k = blockIdx.y;
    int b = blockIdx.z;
    int d = threadIdx.x;
    int l0 = chunk * CHL;
    __shared__ float sx[CHL * XSTR];
    const float4* gx = (const float4*)(xdbl + ((size_t)((b * KK + k) << 12) + l0) * XSTR);
    float4* sx4 = (float4*)sx;
    for (int idx = d; idx < CHL * (XSTR / 4); idx += DI) sx4[idx] = gx[idx];

    float wr[RR];
    #pragma unroll
    for (int r = 0; r < RR; ++r) wr[r] = dtw[(k * DI + d) * RR + r];
    float bias = dtb[k * DI + d];
    // Check An[n] == -(n+1) (holds for A = arange(1..16); 100x ulp tolerance)
    const float* alog = A_logs + (size_t)(k * DI + d) * NS;
    bool fastA = true;
    #pragma unroll
    for (int n = 0; n < NS; ++n) {
        float an = -__expf(alog[n]);
        fastA = fastA && (fabsf(an + (float)(n + 1)) < 1e-4f * (float)(n + 1));
    }
    float h[NS];
    int row = (b * KK + k) * DI + d;
    if (PHASE == 1) {
        #pragma unroll
        for (int n = 0; n < NS; ++n) h[n] = 0.f;
    } else {
        #pragma unroll
        for (int n = 0; n < NS; ++n) h[n] = carryB[((size_t)chunk * NROW + row) * NS + n];
    }
    float Dk = (PHASE == 3) ? Ds[k * DI + d] : 0.f;
    float sumDelta = 0.f;
    const float* ubase = xconv + (size_t)(b << 12) * DI + d;
    float* ybase = y_acc + (size_t)(b << 12) * DI + d;
    __syncthreads();

    int p_cur = pix_of(k, l0);
    float u_cur = ubase[(size_t)p_cur * DI];
    for (int i = 0; i < CHL; ++i) {
        int p_nxt = 0; float u_nxt = 0.f;
        if (i + 1 < CHL) {
            p_nxt = pix_of(k, l0 + i + 1);
            u_nxt = ubase[(size_t)p_nxt * DI];
        }
        float xrv[XSTR];
        float4* x4 = (float4*)xrv;
        constexpr int NV = (PHASE == 3) ? (XSTR / 4) : 6;   // dt+B only in phase 1
        #pragma unroll
        for (int j = 0; j < NV; ++j) x4[j] = sx4[i * (XSTR / 4) + j];
        float dtraw = bias;
        #pragma unroll
        for (int r = 0; r < RR; ++r) dtraw += xrv[r] * wr[r];
        float delta = softplus_f(dtraw);
        if (PHASE == 1) sumDelta += delta;
        float du = delta * u_cur;
        float y = 0.f;
        if (fastA) {
            float g = __expf(-delta);
            float a = 1.f;
            #pragma unroll
            for (int n = 0; n < NS; ++n) {
                a *= g;                       // a = g^(n+1) = exp(-(n+1)*delta)
                h[n] = a * h[n] + du * xrv[6 + n];
                if (PHASE == 3) y += h[n] * xrv[22 + n];
            }
        } else {
            #pragma unroll
            for (int n = 0; n < NS; ++n) {
                float a = __expf(delta * (-__expf(alog[n])));
                h[n] = a * h[n] + du * xrv[6 + n];
                if (PHASE == 3) y += h[n] * xrv[22 + n];
            }
        }
        if (PHASE == 3) {
            y += u_cur * Dk;
            atomicAdd(&ybase[(size_t)p_cur * DI], y);
        }
        p_cur = p_nxt;
        u_cur = u_nxt;
    }
    if (PHASE == 1) {
        #pragma unroll
        for (int n = 0; n < NS; ++n) {
            // prod_i exp(An*delta_i) == exp(An * sum delta_i)  (exact identity)
            float An = -__expf(alog[n]);
            carryA[((size_t)chunk * NROW + row) * NS + n] = __expf(An * sumDelta);
            carryB[((size_t)chunk * NROW + row) * NS + n] = h[n];
        }
    }
}

// ---------------- Phase 2: sequential scan over chunk carries ----------------
template<int NCHT>
__global__ __launch_bounds__(256)
void scan_chunks(const float* __restrict__ carryA, float* __restrict__ carryB) {
    int t = blockIdx.x * 256 + threadIdx.x;
    if (t >= NROW * NS) return;
    float h = 0.f;
    for (int c = 0; c < NCHT; ++c) {
        size_t idx = (size_t)c * (NROW * NS) + t;
        float a = carryA[idx], bb = carryB[idx];
        carryB[idx] = h;       // exclusive prefix = h_in for chunk c
        h = a * h + bb;
    }
}

// ---------------- LayerNorm * z ----------------
__global__ __launch_bounds__(256)
void ln_kernel(const float* __restrict__ y_acc, const float* __restrict__ z_silu,
               const float* __restrict__ nw, const float* __restrict__ nb,
               float* __restrict__ out) {
    int pg = blockIdx.x * 4 + (threadIdx.x >> 6);
    int lane = threadIdx.x & 63;
    const float* yr = y_acc + (size_t)pg * DI;
    float v0 = yr[lane], v1 = yr[lane + 64], v2 = yr[lane + 128];
    float s = v0 + v1 + v2;
    float sq = v0 * v0 + v1 * v1 + v2 * v2;
    #pragma unroll
    for (int m = 32; m >= 1; m >>= 1) {
        s  += __shfl_xor(s, m, 64);
        sq += __shfl_xor(sq, m, 64);
    }
    float mu = s * (1.f / 192.f);
    float var = sq * (1.f / 192.f) - mu * mu;
    float rs = rsqrtf(var + 1e-5f);
    const float* zr = z_silu + (size_t)pg * DI;
    float* o = out + (size_t)pg * DI;
    float vv[3] = {v0, v1, v2};
    #pragma unroll
    for (int j = 0; j < 3; ++j) {
        int c = lane + j * 64;
        o[c] = (nw[c] * (vv[j] - mu) * rs + nb[c]) * zr[c];
    }
}

extern "C" void kernel_launch(void* const* d_in, const int* in_sizes, int n_in,
                              void* d_out, int out_size, void* d_ws, size_t ws_size,
                              hipStream_t stream) {
    const float* x        = (const float*)d_in[0];
    const float* in_projw = (const float*)d_in[1];
    const float* conv_w   = (const float*)d_in[2];
    const float* conv_b   = (const float*)d_in[3];
    const float* x_projw  = (const float*)d_in[4];
    const float* dt_w     = (const float*)d_in[5];
    const float* dt_b     = (const float*)d_in[6];
    const float* A_logs   = (const float*)d_in[7];
    const float* Ds       = (const float*)d_in[8];
    const float* nw       = (const float*)d_in[9];
    const float* nb       = (const float*)d_in[10];
    const float* opw      = (const float*)d_in[11];
    float* out = (float*)d_out;
    float* ws = (float*)d_ws;

    const size_t SZ = (size_t)B_ * LL * DI;          // 3,145,728
    const size_t XD = (size_t)B_ * KK * LL * XSTR;   // 2,621,440

    // choose chunk count by available workspace
    const size_t car128 = (size_t)NROW * 128 * NS;   // 6,291,456 floats
    const size_t need128 = (3 * SZ + XD + 2 * car128) * sizeof(float);
    bool big = (ws_size >= need128);

    float* z_silu = ws;
    float* xc_raw = ws + SZ;            // reused as y_acc
    float* xconv  = ws + 2 * SZ;        // reused as yln after phase 3
    float* xdbl   = ws + 3 * SZ;
    float* carryA = ws + 3 * SZ + XD;
    float* carryB = carryA + (big ? car128 : (size_t)NROW * 64 * NS);
    float* y_acc  = xc_raw;
    float* yln    = xconv;

    gemm_kernel<0><<<dim3(6, 256), 256, 0, stream>>>(x, in_projw, xc_raw, z_silu,
                                                     B_ * LL, 2 * DI, DM);
    conv_kernel<<<dim3(LL / 8, B_), DI, 0, stream>>>(xc_raw, conv_w, conv_b, xconv);
    xdbl_kernel<<<dim3(LL / 128, KK, B_), 256, 0, stream>>>(xconv, x_projw, xdbl);

    if (big) {
        scan_phase<1, 128><<<dim3(128, KK, B_), DI, 0, stream>>>(xconv, xdbl, dt_w, dt_b,
                                                                 A_logs, Ds, carryA, carryB, nullptr);
        scan_chunks<128><<<(NROW * NS + 255) / 256, 256, 0, stream>>>(carryA, carryB);
        hipMemsetAsync(y_acc, 0, SZ * sizeof(float), stream);
        scan_phase<3, 128><<<dim3(128, KK, B_), DI, 0, stream>>>(xconv, xdbl, dt_w, dt_b,
                                                                 A_logs, Ds, carryA, carryB, y_acc);
    } else {
        scan_phase<1, 64><<<dim3(64, KK, B_), DI, 0, stream>>>(xconv, xdbl, dt_w, dt_b,
                                                               A_logs, Ds, carryA, carryB, nullptr);
        scan_chunks<64><<<(NROW * NS + 255) / 256, 256, 0, stream>>>(carryA, carryB);
        hipMemsetAsync(y_acc, 0, SZ * sizeof(float), stream);
        scan_phase<3, 64><<<dim3(64, KK, B_), DI, 0, stream>>>(xconv, xdbl, dt_w, dt_b,
                                                               A_logs, Ds, carryA, carryB, y_acc);
    }
    ln_kernel<<<(B_ * LL) / 4, 256, 0, stream>>>(y_acc, z_silu, nw, nb, yln);
    gemm_kernel<1><<<dim3(2, 256), 256, 0, stream>>>(yln, opw, out, nullptr,
                                                     B_ * LL, DM, DI);
}

// Round 5
// 219.375 us; speedup vs baseline: 2.5456x; 1.1563x over previous
//
#include <hip/hip_runtime.h>
#include <math.h>

// Problem constants
#define B_ 4
#define HH 64
#define WW 64
#define LL 4096          // H*W
#define DM 96            // d_model
#define DI 192           // d_inner
#define NS 16            // n_state
#define RR 6             // r_rank
#define KK 4             // directions
#define NROW (B_ * KK * DI)   // 3072 scan rows
#define XPS 160          // xdblP row stride per pixel (4 dirs x 40)
#define KOFF 40          // per-direction block within a row (38 real + 2 pad)

__device__ __forceinline__ int pix_of(int k, int l) {
    switch (k) {
        case 0: return l;
        case 1: { int w = l >> 6, h = l & 63; return (h << 6) + w; }
        case 2: return (LL - 1) - l;
        default: { int ll = (LL - 1) - l; int w = ll >> 6, h = ll & 63; return (h << 6) + w; }
    }
}

// Fast math (native v_exp_f32 / v_log_f32 / v_rcp_f32)
__device__ __forceinline__ float silu_f(float v) {
    return v * __fdividef(1.f, 1.f + __expf(-v));
}
__device__ __forceinline__ float softplus_f(float x) {
    return (x > 20.f) ? x : __logf(1.f + __expf(x));
}

// ---------------- GEMM: C[M,N] = A[M,K] * Bw[N,K]^T ----------------
// Transposed LDS tiles (k-major): inner loop = 2x ds_read_b128 + 16 FMA.
// MODE 0: in_proj epilogue (n<192 -> C0 raw; else silu -> C1)
// MODE 1: plain store C0[M,N]
// MODE 2: xdbl epilogue: n<152 -> C0[m*160 + (n/38)*40 + n%38]
template<int MODE>
__global__ __launch_bounds__(256)
void gemm_kernel(const float* __restrict__ A, const float* __restrict__ Bw,
                 float* __restrict__ C0, float* __restrict__ C1,
                 int M, int N, int Kd) {
    __shared__ float As[32][68];   // [k][m] ; 68*4B = 17*16B -> b128-aligned rows
    __shared__ float Bs[32][68];   // [k][n]
    int tid = threadIdx.x;
    int tx = tid & 15, ty = tid >> 4;
    int m0 = blockIdx.y * 64, n0 = blockIdx.x * 64;
    float acc[4][4] = {};
    for (int k0 = 0; k0 < Kd; k0 += 32) {
        #pragma unroll
        for (int i = 0; i < 8; ++i) {
            int idx = tid + i * 256;
            int r = idx >> 5, c = idx & 31;
            As[c][r] = A[(size_t)(m0 + r) * Kd + k0 + c];
            int rn = n0 + r;
            Bs[c][r] = (rn < N) ? Bw[(size_t)rn * Kd + k0 + c] : 0.f;
        }
        __syncthreads();
        #pragma unroll
        for (int kk = 0; kk < 32; ++kk) {
            float4 av = *(const float4*)&As[kk][ty * 4];
            float4 bv = *(const float4*)&Bs[kk][tx * 4];
            const float* avp = (const float*)&av;
            const float* bvp = (const float*)&bv;
            #pragma unroll
            for (int i = 0; i < 4; ++i)
                #pragma unroll
                for (int j = 0; j < 4; ++j)
                    acc[i][j] += avp[i] * bvp[j];
        }
        __syncthreads();
    }
    #pragma unroll
    for (int i = 0; i < 4; ++i) {
        int m = m0 + ty * 4 + i;
        #pragma unroll
        for (int j = 0; j < 4; ++j) {
            int n = n0 + tx * 4 + j;
            if (n >= N) continue;
            float v = acc[i][j];
            if (MODE == 0) {
                if (n < DI) C0[(size_t)m * DI + n] = v;
                else        C1[(size_t)m * DI + (n - DI)] = silu_f(v);
            } else if (MODE == 1) {
                C0[(size_t)m * N + n] = v;
            } else {
                if (n < 152) {
                    int kd = n / 38, c = n - kd * 38;
                    C0[(size_t)m * XPS + kd * KOFF + c] = v;
                }
            }
        }
    }
}

// ---------------- Depthwise 3x3 conv + bias + SiLU, 8-pixel row tile ----------------
__global__ __launch_bounds__(192)
void conv_kernel(const float* __restrict__ xc, const float* __restrict__ cw,
                 const float* __restrict__ cb, float* __restrict__ out) {
    int p0 = blockIdx.x * 8;     // 8 pixels, same row (8 | 64)
    int b = blockIdx.y;
    int c = threadIdx.x;
    int h = p0 >> 6, w0 = p0 & 63;
    float kw[9];
    #pragma unroll
    for (int j = 0; j < 9; ++j) kw[j] = cw[c * 9 + j];
    float xv[3][10];
    #pragma unroll
    for (int dh = 0; dh < 3; ++dh) {
        int hh = h + dh - 1;
        bool hv = (hh >= 0 && hh < HH);
        #pragma unroll
        for (int j = 0; j < 10; ++j) {
            int ww = w0 + j - 1;
            bool v = hv && (ww >= 0 && ww < WW);
            xv[dh][j] = v ? xc[((size_t)(b << 12) + (hh << 6) + ww) * DI + c] : 0.f;
        }
    }
    float bias = cb[c];
    #pragma unroll
    for (int w = 0; w < 8; ++w) {
        float acc = bias;
        #pragma unroll
        for (int dh = 0; dh < 3; ++dh)
            #pragma unroll
            for (int dc = 0; dc < 3; ++dc)
                acc += xv[dh][w + dc] * kw[dh * 3 + dc];
        out[((size_t)(b << 12) + p0 + w) * DI + c] = silu_f(acc);
    }
}

// ---------------- Scan phases ----------------
// xdblP layout: [b*4096+p][160], direction k's 38 values at offset k*40.
// carry layout: [chunk][row][n], row = (b*K+k)*DI+d
template<int PHASE, int NCHT>
__global__ __launch_bounds__(192)
void scan_phase(const float* __restrict__ xconv, const float* __restrict__ xdblP,
                const float* __restrict__ dtw, const float* __restrict__ dtb,
                const float* __restrict__ A_logs, const float* __restrict__ Ds,
                float* __restrict__ carryA, float* __restrict__ carryB,
                float* __restrict__ y_acc) {
    constexpr int CHL = LL / NCHT;
    constexpr int NV4 = (PHASE == 3) ? (KOFF / 4) : 6;   // float4s staged per step
    int chunk = blockIdx.x;
    int k = blockIdx.y;
    int b = blockIdx.z;
    int d = threadIdx.x;
    int l0 = chunk * CHL;
    __shared__ float sx[CHL * NV4 * 4];
    float4* sx4 = (float4*)sx;
    const float* xb = xdblP + ((size_t)(b << 12)) * XPS + k * KOFF;
    for (int idx = d; idx < CHL * NV4; idx += DI) {
        int r = idx / NV4, j = idx - r * NV4;
        int p = pix_of(k, l0 + r);
        sx4[idx] = *(const float4*)(xb + (size_t)p * XPS + j * 4);
    }

    float wr[RR];
    #pragma unroll
    for (int r = 0; r < RR; ++r) wr[r] = dtw[(k * DI + d) * RR + r];
    float bias = dtb[k * DI + d];
    // Check An[n] == -(n+1) (holds for A = arange(1..16); 100x ulp tolerance)
    const float* alog = A_logs + (size_t)(k * DI + d) * NS;
    bool fastA = true;
    #pragma unroll
    for (int n = 0; n < NS; ++n) {
        float an = -__expf(alog[n]);
        fastA = fastA && (fabsf(an + (float)(n + 1)) < 1e-4f * (float)(n + 1));
    }
    float h[NS];
    int row = (b * KK + k) * DI + d;
    if (PHASE == 1) {
        #pragma unroll
        for (int n = 0; n < NS; ++n) h[n] = 0.f;
    } else {
        #pragma unroll
        for (int n = 0; n < NS; ++n) h[n] = carryB[((size_t)chunk * NROW + row) * NS + n];
    }
    float Dk = (PHASE == 3) ? Ds[k * DI + d] : 0.f;
    float sumDelta = 0.f;
    const float* ubase = xconv + (size_t)(b << 12) * DI + d;
    float* ybase = y_acc + (size_t)(b << 12) * DI + d;
    __syncthreads();

    int p_cur = pix_of(k, l0);
    float u_cur = ubase[(size_t)p_cur * DI];
    for (int i = 0; i < CHL; ++i) {
        int p_nxt = 0; float u_nxt = 0.f;
        if (i + 1 < CHL) {
            p_nxt = pix_of(k, l0 + i + 1);
            u_nxt = ubase[(size_t)p_nxt * DI];
        }
        float xrv[NV4 * 4];
        float4* x4 = (float4*)xrv;
        #pragma unroll
        for (int j = 0; j < NV4; ++j) x4[j] = sx4[i * NV4 + j];
        float dtraw = bias;
        #pragma unroll
        for (int r = 0; r < RR; ++r) dtraw += xrv[r] * wr[r];
        float delta = softplus_f(dtraw);
        if (PHASE == 1) sumDelta += delta;
        float du = delta * u_cur;
        float y = 0.f;
        if (fastA) {
            float g = __expf(-delta);
            float a = 1.f;
            #pragma unroll
            for (int n = 0; n < NS; ++n) {
                a *= g;                       // a = g^(n+1) = exp(-(n+1)*delta)
                h[n] = a * h[n] + du * xrv[6 + n];
                if (PHASE == 3) y += h[n] * xrv[22 + n];
            }
        } else {
            #pragma unroll
            for (int n = 0; n < NS; ++n) {
                float a = __expf(delta * (-__expf(alog[n])));
                h[n] = a * h[n] + du * xrv[6 + n];
                if (PHASE == 3) y += h[n] * xrv[22 + n];
            }
        }
        if (PHASE == 3) {
            y += u_cur * Dk;
            atomicAdd(&ybase[(size_t)p_cur * DI], y);
        }
        p_cur = p_nxt;
        u_cur = u_nxt;
    }
    if (PHASE == 1) {
        #pragma unroll
        for (int n = 0; n < NS; ++n) {
            // prod_i exp(An*delta_i) == exp(An * sum delta_i)  (exact identity)
            float An = -__expf(alog[n]);
            carryA[((size_t)chunk * NROW + row) * NS + n] = __expf(An * sumDelta);
            carryB[((size_t)chunk * NROW + row) * NS + n] = h[n];
        }
    }
}

// ---------------- Phase 2: sequential scan over chunk carries ----------------
template<int NCHT>
__global__ __launch_bounds__(256)
void scan_chunks(const float* __restrict__ carryA, float* __restrict__ carryB) {
    int t = blockIdx.x * 256 + threadIdx.x;
    if (t >= NROW * NS) return;
    float h = 0.f;
    for (int c = 0; c < NCHT; ++c) {
        size_t idx = (size_t)c * (NROW * NS) + t;
        float a = carryA[idx], bb = carryB[idx];
        carryB[idx] = h;       // exclusive prefix = h_in for chunk c
        h = a * h + bb;
    }
}

// ---------------- LayerNorm * z ----------------
__global__ __launch_bounds__(256)
void ln_kernel(const float* __restrict__ y_acc, const float* __restrict__ z_silu,
               const float* __restrict__ nw, const float* __restrict__ nb,
               float* __restrict__ out) {
    int pg = blockIdx.x * 4 + (threadIdx.x >> 6);
    int lane = threadIdx.x & 63;
    const float* yr = y_acc + (size_t)pg * DI;
    float v0 = yr[lane], v1 = yr[lane + 64], v2 = yr[lane + 128];
    float s = v0 + v1 + v2;
    float sq = v0 * v0 + v1 * v1 + v2 * v2;
    #pragma unroll
    for (int m = 32; m >= 1; m >>= 1) {
        s  += __shfl_xor(s, m, 64);
        sq += __shfl_xor(sq, m, 64);
    }
    float mu = s * (1.f / 192.f);
    float var = sq * (1.f / 192.f) - mu * mu;
    float rs = rsqrtf(var + 1e-5f);
    const float* zr = z_silu + (size_t)pg * DI;
    float* o = out + (size_t)pg * DI;
    float vv[3] = {v0, v1, v2};
    #pragma unroll
    for (int j = 0; j < 3; ++j) {
        int c = lane + j * 64;
        o[c] = (nw[c] * (vv[j] - mu) * rs + nb[c]) * zr[c];
    }
}

extern "C" void kernel_launch(void* const* d_in, const int* in_sizes, int n_in,
                              void* d_out, int out_size, void* d_ws, size_t ws_size,
                              hipStream_t stream) {
    const float* x        = (const float*)d_in[0];
    const float* in_projw = (const float*)d_in[1];
    const float* conv_w   = (const float*)d_in[2];
    const float* conv_b   = (const float*)d_in[3];
    const float* x_projw  = (const float*)d_in[4];
    const float* dt_w     = (const float*)d_in[5];
    const float* dt_b     = (const float*)d_in[6];
    const float* A_logs   = (const float*)d_in[7];
    const float* Ds       = (const float*)d_in[8];
    const float* nw       = (const float*)d_in[9];
    const float* nb       = (const float*)d_in[10];
    const float* opw      = (const float*)d_in[11];
    float* out = (float*)d_out;
    float* ws = (float*)d_ws;

    const size_t SZ = (size_t)B_ * LL * DI;          // 3,145,728
    const size_t XD = (size_t)B_ * LL * XPS;         // 2,621,440

    // choose chunk count by available workspace
    const size_t car128 = (size_t)NROW * 128 * NS;   // 6,291,456 floats
    const size_t need128 = (3 * SZ + XD + 2 * car128) * sizeof(float);
    bool big = (ws_size >= need128);

    float* z_silu = ws;
    float* xc_raw = ws + SZ;            // reused as y_acc
    float* xconv  = ws + 2 * SZ;        // reused as yln after phase 3
    float* xdblP  = ws + 3 * SZ;
    float* carryA = ws + 3 * SZ + XD;
    float* carryB = carryA + (big ? car128 : (size_t)NROW * 64 * NS);
    float* y_acc  = xc_raw;
    float* yln    = xconv;

    gemm_kernel<0><<<dim3(6, 256), 256, 0, stream>>>(x, in_projw, xc_raw, z_silu,
                                                     B_ * LL, 2 * DI, DM);
    conv_kernel<<<dim3(LL / 8, B_), DI, 0, stream>>>(xc_raw, conv_w, conv_b, xconv);
    // x_dbl for all 4 directions in one pixel-order GEMM (152 = 4*38 outputs)
    gemm_kernel<2><<<dim3(3, 256), 256, 0, stream>>>(xconv, x_projw, xdblP, nullptr,
                                                     B_ * LL, 152, DI);

    if (big) {
        scan_phase<1, 128><<<dim3(128, KK, B_), DI, 0, stream>>>(xconv, xdblP, dt_w, dt_b,
                                                                 A_logs, Ds, carryA, carryB, nullptr);
        scan_chunks<128><<<(NROW * NS + 255) / 256, 256, 0, stream>>>(carryA, carryB);
        hipMemsetAsync(y_acc, 0, SZ * sizeof(float), stream);
        scan_phase<3, 128><<<dim3(128, KK, B_), DI, 0, stream>>>(xconv, xdblP, dt_w, dt_b,
                                                                 A_logs, Ds, carryA, carryB, y_acc);
    } else {
        scan_phase<1, 64><<<dim3(64, KK, B_), DI, 0, stream>>>(xconv, xdblP, dt_w, dt_b,
                                                               A_logs, Ds, carryA, carryB, nullptr);
        scan_chunks<64><<<(NROW * NS + 255) / 256, 256, 0, stream>>>(carryA, carryB);
        hipMemsetAsync(y_acc, 0, SZ * sizeof(float), stream);
        scan_phase<3, 64><<<dim3(64, KK, B_), DI, 0, stream>>>(xconv, xdblP, dt_w, dt_b,
                                                               A_logs, Ds, carryA, carryB, y_acc);
    }
    ln_kernel<<<(B_ * LL) / 4, 256, 0, stream>>>(y_acc, z_silu, nw, nb, yln);
    gemm_kernel<1><<<dim3(2, 256), 256, 0, stream>>>(yln, opw, out, nullptr,
                                                     B_ * LL, DM, DI);
}